// Round 6
// baseline (231.374 us; speedup 1.0000x reference)
//
#include <hip/hip_runtime.h>

// LIF forward: x [B=32, T=16, N=65536] f32, thresh scalar f32 -> spikes [B,T,N] f32
//   mem = mem*TAU + x[t];  spike = (mem > thresh);  mem = spike ? 0 : mem;
//
// R1: latency-bound; VGPR=20, ~2 loads in flight, 2.5 TB/s (fill kernel: 6.7).
// R2: source-order preload array -> scheduler re-sank the loads. no change.
// R5: sched_barrier(0) -> VGPR still 24, loads still serialized. FAILED.
// R6: pin each loaded value with volatile asm "+v" (rule #17): the asm
//     REDEFINES the value, compute consumes the asm result -> loads must all
//     issue + complete before their pin; memory ops can't cross volatile asm.
//     Register allocator is forced to keep 32 data VGPRs live -> 16 loads
//     in flight/wave. launch_bounds(256,8) caps VGPR<=64 -> 8 waves/SIMD.

#define TAU 0.25f

typedef float f32x2 __attribute__((ext_vector_type(2)));

__global__ __launch_bounds__(256, 8) void lif_fwd_kernel(
    const f32x2* __restrict__ x,
    const float* __restrict__ thresh,
    f32x2* __restrict__ out)
{
    constexpr int T  = 16;
    constexpr int N2 = 65536 / 2;   // 32768 float2 per (b,t) row

    const int gid = blockIdx.x * blockDim.x + threadIdx.x;  // 0 .. B*N2-1
    const int b   = gid >> 15;          // gid / N2
    const int n2  = gid & (N2 - 1);     // gid % N2

    const float th = thresh[0];

    const size_t base = (size_t)b * T * N2 + n2;
    const f32x2* xp = x   + base;
    f32x2*       op = out + base;

    // Issue all 16 independent loads.
    float ax[T], ay[T];
#pragma unroll
    for (int t = 0; t < T; ++t) {
        f32x2 v = xp[(size_t)t * N2];
        ax[t] = v.x;
        ay[t] = v.y;
    }

    // Pin: volatile asm redefines each value. Compute below consumes the asm
    // outputs -> cannot be hoisted above; loads cannot sink below (memory ops
    // don't cross volatile asm). Forces 32 data VGPRs live = 16 loads in
    // flight with counted in-order vmcnt waits.
#pragma unroll
    for (int t = 0; t < T; ++t)
        asm volatile("" : "+v"(ax[t]), "+v"(ay[t]));

    float mx = 0.f, my = 0.f;

#pragma unroll
    for (int t = 0; t < T; ++t) {
        mx = mx * TAU + ax[t];
        my = my * TAU + ay[t];

        const bool px = mx > th;
        const bool py = my > th;

        f32x2 s;
        s.x = px ? 1.f : 0.f;
        s.y = py ? 1.f : 0.f;

        mx = px ? 0.f : mx;
        my = py ? 0.f : my;

        // Output never re-read: non-temporal keeps L2/L3 for the x stream.
        __builtin_nontemporal_store(s, &op[(size_t)t * N2]);
    }
}

extern "C" void kernel_launch(void* const* d_in, const int* in_sizes, int n_in,
                              void* d_out, int out_size, void* d_ws, size_t ws_size,
                              hipStream_t stream)
{
    const float* x      = (const float*)d_in[0];
    const float* thresh = (const float*)d_in[1];
    float*       out    = (float*)d_out;

    // total = B*T*N = 33,554,432 ; threads = B*N/2 = total/(16*2) = 1,048,576
    const int total   = in_sizes[0];
    const int threads = total / (16 * 2);
    const int block   = 256;
    const int grid    = threads / block;   // 4096 blocks

    lif_fwd_kernel<<<grid, block, 0, stream>>>(
        (const f32x2*)x, thresh, (f32x2*)out);
}